// Round 1
// baseline (1598.072 us; speedup 1.0000x reference)
//
#include <hip/hip_runtime.h>

#define HID 64
#define NGRAPHS 256

// ---- degree / norm precompute -------------------------------------------

__global__ __launch_bounds__(256) void k_init_deg(float* deg, int n) {
    int i = blockIdx.x * 256 + threadIdx.x;
    if (i < n) deg[i] = 1.0f;                 // self-loop contributes 1
}

__global__ __launch_bounds__(256) void k_count_deg(const int* __restrict__ dst,
                                                   float* deg, int e) {
    int i = blockIdx.x * 256 + threadIdx.x;
    if (i < e) atomicAdd(&deg[dst[i]], 1.0f);
}

__global__ __launch_bounds__(256) void k_dinv(float* deg, int n) {
    int i = blockIdx.x * 256 + threadIdx.x;
    if (i < n) deg[i] = rsqrtf(deg[i]);       // deg >= 1 always (self-loops)
}

__global__ __launch_bounds__(256) void k_norm(const int* __restrict__ src,
                                              const int* __restrict__ dst,
                                              const float* __restrict__ dinv,
                                              float* __restrict__ norm, int e) {
    int i = blockIdx.x * 256 + threadIdx.x;
    if (i < e) norm[i] = dinv[src[i]] * dinv[dst[i]];
}

// ---- per-layer dense transform + agg init -------------------------------
// h = (relu?)act @ W ; agg_init = b + h * dinv^2   (self-loop folded in)
// Block handles 32 node rows; input rows staged in LDS first, so act and agg
// may alias (in-place ping-pong between the two N x 64 buffers).

template <int K, bool RELU>
__global__ __launch_bounds__(256) void k_gemm_init(
        const float* __restrict__ act, const float* __restrict__ W,
        const float* __restrict__ b, const float* __restrict__ dinv,
        float* __restrict__ h, float* __restrict__ agg, int n_nodes) {
    __shared__ float Wsh[K * HID];
    __shared__ float Ash[32 * K];
    const int t = threadIdx.x;
    const int n0 = blockIdx.x * 32;

    for (int i = t; i < K * HID; i += 256) Wsh[i] = W[i];
    const long long lim = (long long)(n_nodes - n0) * K;
    for (int i = t; i < 32 * K; i += 256) {
        float v = (i < lim) ? act[(size_t)n0 * K + i] : 0.0f;
        if (RELU) v = fmaxf(v, 0.0f);
        Ash[i] = v;
    }
    __syncthreads();

    const int c = t & 63;       // output channel
    const int ng = t >> 6;      // node sub-group 0..3, 8 nodes each
    float acc[8];
#pragma unroll
    for (int i = 0; i < 8; i++) acc[i] = 0.0f;
#pragma unroll
    for (int k = 0; k < K; k++) {
        float w = Wsh[k * HID + c];
#pragma unroll
        for (int i = 0; i < 8; i++) acc[i] += Ash[(ng * 8 + i) * K + k] * w;
    }
    const float bc = b[c];
#pragma unroll
    for (int i = 0; i < 8; i++) {
        int n = n0 + ng * 8 + i;
        if (n < n_nodes) {
            float dv = dinv[n];
            float hv = acc[i];
            h[(size_t)n * HID + c] = hv;
            agg[(size_t)n * HID + c] = bc + hv * dv * dv;
        }
    }
}

// ---- edge scatter: one wave (64 lanes = 64 channels) per edge -----------

__global__ __launch_bounds__(256) void k_scatter(
        const int* __restrict__ src, const int* __restrict__ dst,
        const float* __restrict__ norm, const float* __restrict__ h,
        float* __restrict__ agg, int n_edges) {
    int wave = (blockIdx.x * 256 + threadIdx.x) >> 6;
    int lane = threadIdx.x & 63;
    if (wave >= n_edges) return;
    int s = src[wave];
    int d = dst[wave];
    float w = norm[wave];
    float v = h[(size_t)s * HID + lane] * w;
    atomicAdd(&agg[(size_t)d * HID + lane], v);
}

// ---- graph mean-pool accumulate: one wave per node ----------------------

__global__ __launch_bounds__(256) void k_pool(
        const float* __restrict__ agg, const int* __restrict__ batch,
        float* __restrict__ pool, float* __restrict__ cnt, int n_nodes) {
    int wave = (blockIdx.x * 256 + threadIdx.x) >> 6;
    int lane = threadIdx.x & 63;
    if (wave >= n_nodes) return;
    int g = batch[wave];
    atomicAdd(&pool[g * HID + lane], agg[(size_t)wave * HID + lane]);
    if (lane == 0) atomicAdd(&cnt[g], 1.0f);
}

// ---- final head: out[g][o] = (sum_c pool[g][c]*Wl[c][o]) / cnt[g] + bl[o]

__global__ __launch_bounds__(256) void k_head(
        const float* __restrict__ pool, const float* __restrict__ cnt,
        const float* __restrict__ Wl, const float* __restrict__ bl,
        float* __restrict__ out) {
    int t = blockIdx.x * 256 + threadIdx.x;   // 0..511
    if (t >= NGRAPHS * 2) return;
    int g = t >> 1, o = t & 1;
    float c = fmaxf(cnt[g], 1.0f);
    float acc = 0.0f;
#pragma unroll
    for (int k = 0; k < HID; k++) acc += pool[g * HID + k] * Wl[k * 2 + o];
    out[t] = acc / c + bl[o];
}

// -------------------------------------------------------------------------

extern "C" void kernel_launch(void* const* d_in, const int* in_sizes, int n_in,
                              void* d_out, int out_size, void* d_ws, size_t ws_size,
                              hipStream_t stream) {
    const float* x     = (const float*)d_in[0];
    const int*   ei    = (const int*)d_in[1];
    const int*   batch = (const int*)d_in[2];
    const float* W1    = (const float*)d_in[3];
    const float* b1    = (const float*)d_in[4];
    const float* W2    = (const float*)d_in[5];
    const float* b2    = (const float*)d_in[6];
    const float* W3    = (const float*)d_in[7];
    const float* b3    = (const float*)d_in[8];
    const float* Wl    = (const float*)d_in[9];
    const float* bl    = (const float*)d_in[10];
    float* out = (float*)d_out;

    const int N = in_sizes[0] / 7;     // 100000
    const int E = in_sizes[1] / 2;     // 1250000
    const int* src = ei;
    const int* dst = ei + E;

    // workspace carve-out (256B aligned)
    char* ws = (char*)d_ws;
    size_t off = 0;
    auto carve = [&](size_t bytes) {
        void* p = ws + off;
        off = (off + bytes + 255) & ~(size_t)255;
        return p;
    };
    float* dinv = (float*)carve((size_t)N * 4);
    float* norm = (float*)carve((size_t)E * 4);
    float* bufH = (float*)carve((size_t)N * HID * 4);
    float* bufA = (float*)carve((size_t)N * HID * 4);
    float* pool = (float*)carve((size_t)(NGRAPHS * HID + NGRAPHS) * 4);
    float* cnt  = pool + NGRAPHS * HID;

    const int nb_n = (N + 255) / 256;
    const int nb_e = (E + 255) / 256;
    const int nb_gemm = (N + 31) / 32;
    const int nb_scat = (E + 3) / 4;       // 4 waves (edges) per 256-thread block
    const int nb_pool = (N + 3) / 4;

    // degree / norm
    k_init_deg<<<nb_n, 256, 0, stream>>>(dinv, N);
    k_count_deg<<<nb_e, 256, 0, stream>>>(dst, dinv, E);
    k_dinv<<<nb_n, 256, 0, stream>>>(dinv, N);
    k_norm<<<nb_e, 256, 0, stream>>>(src, dst, dinv, norm, E);

    // layer 1: x (N x 7) -> bufH, agg init in bufA
    k_gemm_init<7, false><<<nb_gemm, 256, 0, stream>>>(x, W1, b1, dinv, bufH, bufA, N);
    k_scatter<<<nb_scat, 256, 0, stream>>>(src, dst, norm, bufH, bufA, E);

    // layer 2: relu(bufA) -> bufH, agg init overwrites bufA (safe: LDS-staged)
    k_gemm_init<HID, true><<<nb_gemm, 256, 0, stream>>>(bufA, W2, b2, dinv, bufH, bufA, N);
    k_scatter<<<nb_scat, 256, 0, stream>>>(src, dst, norm, bufH, bufA, E);

    // layer 3: relu(bufA) -> bufH, agg init overwrites bufA
    k_gemm_init<HID, true><<<nb_gemm, 256, 0, stream>>>(bufA, W3, b3, dinv, bufH, bufA, N);
    k_scatter<<<nb_scat, 256, 0, stream>>>(src, dst, norm, bufH, bufA, E);

    // mean-pool + head
    hipMemsetAsync(pool, 0, (size_t)(NGRAPHS * HID + NGRAPHS) * 4, stream);
    k_pool<<<nb_pool, 256, 0, stream>>>(bufA, batch, pool, cnt, N);
    k_head<<<2, 256, 0, stream>>>(pool, cnt, Wl, bl, out);
}

// Round 2
// 1211.027 us; speedup vs baseline: 1.3196x; 1.3196x over previous
//
#include <hip/hip_runtime.h>

#define HID 64
#define NGRAPHS 256

// ---- degree / norm precompute -------------------------------------------

__global__ __launch_bounds__(256) void k_init_deg(float* deg, int n) {
    int i = blockIdx.x * 256 + threadIdx.x;
    if (i < n) deg[i] = 1.0f;                 // self-loop contributes 1
}

__global__ __launch_bounds__(256) void k_count_deg(const int* __restrict__ dst,
                                                   float* deg, int e) {
    int i = blockIdx.x * 256 + threadIdx.x;
    if (i < e) atomicAdd(&deg[dst[i]], 1.0f);
}

__global__ __launch_bounds__(256) void k_dinv(float* deg, int n) {
    int i = blockIdx.x * 256 + threadIdx.x;
    if (i < n) deg[i] = rsqrtf(deg[i]);       // deg >= 1 always (self-loops)
}

__global__ __launch_bounds__(256) void k_norm(const int* __restrict__ src,
                                              const int* __restrict__ dst,
                                              const float* __restrict__ dinv,
                                              float* __restrict__ norm, int e) {
    int i = blockIdx.x * 256 + threadIdx.x;
    if (i < e) norm[i] = dinv[src[i]] * dinv[dst[i]];
}

// ---- per-layer dense transform + agg init -------------------------------
// h = (relu?)act @ W ; agg_init = b + h * dinv^2   (self-loop folded in)
// Block handles 32 node rows; input rows staged in LDS first, so act and agg
// may alias (in-place ping-pong between the two N x 64 buffers).

template <int K, bool RELU>
__global__ __launch_bounds__(256) void k_gemm_init(
        const float* __restrict__ act, const float* __restrict__ W,
        const float* __restrict__ b, const float* __restrict__ dinv,
        float* __restrict__ h, float* __restrict__ agg, int n_nodes) {
    __shared__ float Wsh[K * HID];
    __shared__ float Ash[32 * K];
    const int t = threadIdx.x;
    const int n0 = blockIdx.x * 32;

    for (int i = t; i < K * HID; i += 256) Wsh[i] = W[i];
    const long long lim = (long long)(n_nodes - n0) * K;
    for (int i = t; i < 32 * K; i += 256) {
        float v = (i < lim) ? act[(size_t)n0 * K + i] : 0.0f;
        if (RELU) v = fmaxf(v, 0.0f);
        Ash[i] = v;
    }
    __syncthreads();

    const int c = t & 63;       // output channel
    const int ng = t >> 6;      // node sub-group 0..3, 8 nodes each
    float acc[8];
#pragma unroll
    for (int i = 0; i < 8; i++) acc[i] = 0.0f;
#pragma unroll
    for (int k = 0; k < K; k++) {
        float w = Wsh[k * HID + c];
#pragma unroll
        for (int i = 0; i < 8; i++) acc[i] += Ash[(ng * 8 + i) * K + k] * w;
    }
    const float bc = b[c];
#pragma unroll
    for (int i = 0; i < 8; i++) {
        int n = n0 + ng * 8 + i;
        if (n < n_nodes) {
            float dv = dinv[n];
            float hv = acc[i];
            h[(size_t)n * HID + c] = hv;
            agg[(size_t)n * HID + c] = bc + hv * dv * dv;
        }
    }
}

// ---- edge scatter: one wave (64 lanes = 64 channels) per edge -----------

__global__ __launch_bounds__(256) void k_scatter(
        const int* __restrict__ src, const int* __restrict__ dst,
        const float* __restrict__ norm, const float* __restrict__ h,
        float* __restrict__ agg, int n_edges) {
    int wave = (blockIdx.x * 256 + threadIdx.x) >> 6;
    int lane = threadIdx.x & 63;
    if (wave >= n_edges) return;
    int s = src[wave];
    int d = dst[wave];
    float w = norm[wave];
    float v = h[(size_t)s * HID + lane] * w;
    atomicAdd(&agg[(size_t)d * HID + lane], v);
}

// ---- graph mean-pool: one wave per 64-node run; batch is SORTED, so
// accumulate in registers across same-graph runs, flush one atomic per run.

__global__ __launch_bounds__(256) void k_pool(
        const float* __restrict__ agg, const int* __restrict__ batch,
        float* __restrict__ pool, float* __restrict__ cnt, int n_nodes) {
    const int NPW = 64;                       // nodes per wave
    int wave = (blockIdx.x * 256 + threadIdx.x) >> 6;
    int lane = threadIdx.x & 63;
    int n0 = wave * NPW;
    if (n0 >= n_nodes) return;
    int nend = min(n0 + NPW, n_nodes);

    int g = batch[n0];
    float acc = 0.0f;
    int cn = 0;
    for (int n = n0; n < nend; n++) {
        int gn = batch[n];
        if (gn != g) {                         // run boundary: flush
            atomicAdd(&pool[g * HID + lane], acc);
            if (lane == 0) atomicAdd(&cnt[g], (float)cn);
            acc = 0.0f; cn = 0; g = gn;
        }
        acc += agg[(size_t)n * HID + lane];
        cn++;
    }
    atomicAdd(&pool[g * HID + lane], acc);
    if (lane == 0) atomicAdd(&cnt[g], (float)cn);
}

// ---- final head: out[g][o] = (sum_c pool[g][c]*Wl[c][o]) / cnt[g] + bl[o]

__global__ __launch_bounds__(256) void k_head(
        const float* __restrict__ pool, const float* __restrict__ cnt,
        const float* __restrict__ Wl, const float* __restrict__ bl,
        float* __restrict__ out) {
    int t = blockIdx.x * 256 + threadIdx.x;   // 0..511
    if (t >= NGRAPHS * 2) return;
    int g = t >> 1, o = t & 1;
    float c = fmaxf(cnt[g], 1.0f);
    float acc = 0.0f;
#pragma unroll
    for (int k = 0; k < HID; k++) acc += pool[g * HID + k] * Wl[k * 2 + o];
    out[t] = acc / c + bl[o];
}

// -------------------------------------------------------------------------

extern "C" void kernel_launch(void* const* d_in, const int* in_sizes, int n_in,
                              void* d_out, int out_size, void* d_ws, size_t ws_size,
                              hipStream_t stream) {
    const float* x     = (const float*)d_in[0];
    const int*   ei    = (const int*)d_in[1];
    const int*   batch = (const int*)d_in[2];
    const float* W1    = (const float*)d_in[3];
    const float* b1    = (const float*)d_in[4];
    const float* W2    = (const float*)d_in[5];
    const float* b2    = (const float*)d_in[6];
    const float* W3    = (const float*)d_in[7];
    const float* b3    = (const float*)d_in[8];
    const float* Wl    = (const float*)d_in[9];
    const float* bl    = (const float*)d_in[10];
    float* out = (float*)d_out;

    const int N = in_sizes[0] / 7;     // 100000
    const int E = in_sizes[1] / 2;     // 1250000
    const int* src = ei;
    const int* dst = ei + E;

    // workspace carve-out (256B aligned)
    char* ws = (char*)d_ws;
    size_t off = 0;
    auto carve = [&](size_t bytes) {
        void* p = ws + off;
        off = (off + bytes + 255) & ~(size_t)255;
        return p;
    };
    float* dinv = (float*)carve((size_t)N * 4);
    float* norm = (float*)carve((size_t)E * 4);
    float* bufH = (float*)carve((size_t)N * HID * 4);
    float* bufA = (float*)carve((size_t)N * HID * 4);
    float* pool = (float*)carve((size_t)(NGRAPHS * HID + NGRAPHS) * 4);
    float* cnt  = pool + NGRAPHS * HID;

    const int nb_n = (N + 255) / 256;
    const int nb_e = (E + 255) / 256;
    const int nb_gemm = (N + 31) / 32;
    const int nb_scat = (E + 3) / 4;       // 4 waves (edges) per 256-thread block
    const int nb_pool = (N + 64 * 4 - 1) / (64 * 4);  // 4 waves/block, 64 nodes/wave

    // degree / norm
    k_init_deg<<<nb_n, 256, 0, stream>>>(dinv, N);
    k_count_deg<<<nb_e, 256, 0, stream>>>(dst, dinv, E);
    k_dinv<<<nb_n, 256, 0, stream>>>(dinv, N);
    k_norm<<<nb_e, 256, 0, stream>>>(src, dst, dinv, norm, E);

    // layer 1: x (N x 7) -> bufH, agg init in bufA
    k_gemm_init<7, false><<<nb_gemm, 256, 0, stream>>>(x, W1, b1, dinv, bufH, bufA, N);
    k_scatter<<<nb_scat, 256, 0, stream>>>(src, dst, norm, bufH, bufA, E);

    // layer 2: relu(bufA) -> bufH, agg init overwrites bufA (safe: LDS-staged)
    k_gemm_init<HID, true><<<nb_gemm, 256, 0, stream>>>(bufA, W2, b2, dinv, bufH, bufA, N);
    k_scatter<<<nb_scat, 256, 0, stream>>>(src, dst, norm, bufH, bufA, E);

    // layer 3: relu(bufA) -> bufH, agg init overwrites bufA
    k_gemm_init<HID, true><<<nb_gemm, 256, 0, stream>>>(bufA, W3, b3, dinv, bufH, bufA, N);
    k_scatter<<<nb_scat, 256, 0, stream>>>(src, dst, norm, bufH, bufA, E);

    // mean-pool + head
    hipMemsetAsync(pool, 0, (size_t)(NGRAPHS * HID + NGRAPHS) * 4, stream);
    k_pool<<<nb_pool, 256, 0, stream>>>(bufA, batch, pool, cnt, N);
    k_head<<<2, 256, 0, stream>>>(pool, cnt, Wl, bl, out);
}

// Round 3
// 679.099 us; speedup vs baseline: 2.3532x; 1.7833x over previous
//
#include <hip/hip_runtime.h>

#define HID 64
#define NGRAPHS 256
#define SCAN_ELEMS 1024   // elements per scan block (256 thr x 4)

// ---- CSR build: histogram -> scan -> fill -------------------------------

__global__ __launch_bounds__(256) void k_hist(const int* __restrict__ dst,
                                              int* __restrict__ deg, int e) {
    int i = blockIdx.x * 256 + threadIdx.x;
    if (i < e) atomicAdd(&deg[dst[i]], 1);
}

__global__ __launch_bounds__(256) void k_dinv(const int* __restrict__ deg,
                                              float* __restrict__ dinv, int n) {
    int i = blockIdx.x * 256 + threadIdx.x;
    if (i < n) dinv[i] = rsqrtf((float)(deg[i] + 1));   // +1 self-loop
}

// exclusive scan, stage 1: per-block (1024 elems) scan + block totals
__global__ __launch_bounds__(256) void k_scan1(const int* __restrict__ deg,
                                               int* __restrict__ rowptr,
                                               int* __restrict__ bsum, int n) {
    __shared__ int sh[256];
    const int t = threadIdx.x;
    const int base = blockIdx.x * SCAN_ELEMS + t * 4;
    int v[4];
    int s = 0;
#pragma unroll
    for (int k = 0; k < 4; k++) {
        int i = base + k;
        v[k] = (i < n) ? deg[i] : 0;
        s += v[k];
    }
    sh[t] = s;
    __syncthreads();
#pragma unroll
    for (int off = 1; off < 256; off <<= 1) {
        int add = (t >= off) ? sh[t - off] : 0;
        __syncthreads();
        sh[t] += add;
        __syncthreads();
    }
    int run = sh[t] - s;    // exclusive prefix of this thread's chunk
#pragma unroll
    for (int k = 0; k < 4; k++) {
        int i = base + k;
        if (i < n) rowptr[i] = run;
        run += v[k];
    }
    if (t == 255) bsum[blockIdx.x] = sh[255];
}

// stage 2: exclusive scan of the (<=128) block totals, single block
__global__ __launch_bounds__(128) void k_scan2(int* __restrict__ bsum, int nb) {
    __shared__ int sh[128];
    const int t = threadIdx.x;
    int own = (t < nb) ? bsum[t] : 0;
    sh[t] = own;
    __syncthreads();
#pragma unroll
    for (int off = 1; off < 128; off <<= 1) {
        int add = (t >= off) ? sh[t - off] : 0;
        __syncthreads();
        sh[t] += add;
        __syncthreads();
    }
    if (t < nb) bsum[t] = sh[t] - own;
}

// stage 3: add block offsets
__global__ __launch_bounds__(256) void k_scan3(int* __restrict__ rowptr,
                                               const int* __restrict__ bsum, int n) {
    int i = blockIdx.x * 256 + threadIdx.x;
    if (i < n) rowptr[i] += bsum[i / SCAN_ELEMS];
}

// fill: pos = rowptr[d]++ ; after this pass rowptr[d] == row END of node d
// (row start of node d is rowptr[d-1], or 0 for d==0)
__global__ __launch_bounds__(256) void k_fill(const int* __restrict__ src,
                                              const int* __restrict__ dst,
                                              const float* __restrict__ dinv,
                                              int* __restrict__ rowptr,
                                              int* __restrict__ csr_src,
                                              float* __restrict__ csr_w, int e) {
    int i = blockIdx.x * 256 + threadIdx.x;
    if (i >= e) return;
    int s = src[i], d = dst[i];
    int pos = atomicAdd(&rowptr[d], 1);
    csr_src[pos] = s;
    csr_w[pos] = dinv[s] * dinv[d];
}

// ---- per-layer dense transform + agg init -------------------------------
// h = (relu?)act @ W ; agg_init = b + h * dinv^2   (self-loop folded in)

template <int K, bool RELU>
__global__ __launch_bounds__(256) void k_gemm_init(
        const float* __restrict__ act, const float* __restrict__ W,
        const float* __restrict__ b, const float* __restrict__ dinv,
        float* __restrict__ h, float* __restrict__ agg, int n_nodes) {
    __shared__ float Wsh[K * HID];
    __shared__ float Ash[32 * K];
    const int t = threadIdx.x;
    const int n0 = blockIdx.x * 32;

    for (int i = t; i < K * HID; i += 256) Wsh[i] = W[i];
    const long long lim = (long long)(n_nodes - n0) * K;
    for (int i = t; i < 32 * K; i += 256) {
        float v = (i < lim) ? act[(size_t)n0 * K + i] : 0.0f;
        if (RELU) v = fmaxf(v, 0.0f);
        Ash[i] = v;
    }
    __syncthreads();

    const int c = t & 63;       // output channel
    const int ng = t >> 6;      // node sub-group 0..3, 8 nodes each
    float acc[8];
#pragma unroll
    for (int i = 0; i < 8; i++) acc[i] = 0.0f;
#pragma unroll
    for (int k = 0; k < K; k++) {
        float w = Wsh[k * HID + c];
#pragma unroll
        for (int i = 0; i < 8; i++) acc[i] += Ash[(ng * 8 + i) * K + k] * w;
    }
    const float bc = b[c];
#pragma unroll
    for (int i = 0; i < 8; i++) {
        int n = n0 + ng * 8 + i;
        if (n < n_nodes) {
            float dv = dinv[n];
            float hv = acc[i];
            h[(size_t)n * HID + c] = hv;
            agg[(size_t)n * HID + c] = bc + hv * dv * dv;
        }
    }
}

// ---- CSR aggregate: one wave per dst node, no atomics -------------------

__global__ __launch_bounds__(256) void k_aggregate(
        const int* __restrict__ rowptr,      // post-fill: rowptr[d] = row END
        const int* __restrict__ csr_src, const float* __restrict__ csr_w,
        const float* __restrict__ h, float* __restrict__ agg, int n_nodes) {
    int wave = (blockIdx.x * 256 + threadIdx.x) >> 6;
    int lane = threadIdx.x & 63;
    if (wave >= n_nodes) return;
    int beg = (wave == 0) ? 0 : rowptr[wave - 1];
    int end = rowptr[wave];
    float acc = agg[(size_t)wave * HID + lane];   // b + self-loop already in
    int j = beg;
    for (; j + 1 < end; j += 2) {                 // 2-wide for MLP
        int s0 = csr_src[j], s1 = csr_src[j + 1];
        float w0 = csr_w[j], w1 = csr_w[j + 1];
        float v0 = h[(size_t)s0 * HID + lane];
        float v1 = h[(size_t)s1 * HID + lane];
        acc += v0 * w0 + v1 * w1;
    }
    if (j < end) {
        int s = csr_src[j];
        acc += h[(size_t)s * HID + lane] * csr_w[j];
    }
    agg[(size_t)wave * HID + lane] = acc;
}

// ---- graph mean-pool: batch sorted -> register runs, few atomics --------

__global__ __launch_bounds__(256) void k_pool(
        const float* __restrict__ agg, const int* __restrict__ batch,
        float* __restrict__ pool, float* __restrict__ cnt, int n_nodes) {
    const int NPW = 64;                       // nodes per wave
    int wave = (blockIdx.x * 256 + threadIdx.x) >> 6;
    int lane = threadIdx.x & 63;
    int n0 = wave * NPW;
    if (n0 >= n_nodes) return;
    int nend = min(n0 + NPW, n_nodes);

    int g = batch[n0];
    float acc = 0.0f;
    int cn = 0;
    for (int n = n0; n < nend; n++) {
        int gn = batch[n];
        if (gn != g) {                         // run boundary: flush
            atomicAdd(&pool[g * HID + lane], acc);
            if (lane == 0) atomicAdd(&cnt[g], (float)cn);
            acc = 0.0f; cn = 0; g = gn;
        }
        acc += agg[(size_t)n * HID + lane];
        cn++;
    }
    atomicAdd(&pool[g * HID + lane], acc);
    if (lane == 0) atomicAdd(&cnt[g], (float)cn);
}

// ---- final head ---------------------------------------------------------

__global__ __launch_bounds__(256) void k_head(
        const float* __restrict__ pool, const float* __restrict__ cnt,
        const float* __restrict__ Wl, const float* __restrict__ bl,
        float* __restrict__ out) {
    int t = blockIdx.x * 256 + threadIdx.x;   // 0..511
    if (t >= NGRAPHS * 2) return;
    int g = t >> 1, o = t & 1;
    float c = fmaxf(cnt[g], 1.0f);
    float acc = 0.0f;
#pragma unroll
    for (int k = 0; k < HID; k++) acc += pool[g * HID + k] * Wl[k * 2 + o];
    out[t] = acc / c + bl[o];
}

// -------------------------------------------------------------------------

extern "C" void kernel_launch(void* const* d_in, const int* in_sizes, int n_in,
                              void* d_out, int out_size, void* d_ws, size_t ws_size,
                              hipStream_t stream) {
    const float* x     = (const float*)d_in[0];
    const int*   ei    = (const int*)d_in[1];
    const int*   batch = (const int*)d_in[2];
    const float* W1    = (const float*)d_in[3];
    const float* b1    = (const float*)d_in[4];
    const float* W2    = (const float*)d_in[5];
    const float* b2    = (const float*)d_in[6];
    const float* W3    = (const float*)d_in[7];
    const float* b3    = (const float*)d_in[8];
    const float* Wl    = (const float*)d_in[9];
    const float* bl    = (const float*)d_in[10];
    float* out = (float*)d_out;

    const int N = in_sizes[0] / 7;     // 100000
    const int E = in_sizes[1] / 2;     // 1250000
    const int* src = ei;
    const int* dst = ei + E;

    // workspace carve-out (256B aligned)
    char* ws = (char*)d_ws;
    size_t off = 0;
    auto carve = [&](size_t bytes) {
        void* p = ws + off;
        off = (off + bytes + 255) & ~(size_t)255;
        return p;
    };
    int*   deg_i   = (int*)carve((size_t)N * 4);
    float* dinv    = (float*)carve((size_t)N * 4);
    int*   rowptr  = (int*)carve((size_t)N * 4);
    int*   bsum    = (int*)carve(512 * 4);
    int*   csr_src = (int*)carve((size_t)E * 4);
    float* csr_w   = (float*)carve((size_t)E * 4);
    float* bufH    = (float*)carve((size_t)N * HID * 4);
    float* bufA    = (float*)carve((size_t)N * HID * 4);
    float* pool    = (float*)carve((size_t)(NGRAPHS * HID + NGRAPHS) * 4);
    float* cnt     = pool + NGRAPHS * HID;

    const int nb_n = (N + 255) / 256;
    const int nb_e = (E + 255) / 256;
    const int nb_gemm = (N + 31) / 32;
    const int nb_scan = (N + SCAN_ELEMS - 1) / SCAN_ELEMS;   // 98
    const int nb_agg  = (N + 3) / 4;       // 4 waves (nodes) per block
    const int nb_pool = (N + 64 * 4 - 1) / (64 * 4);

    // ---- CSR build (once, reused by all 3 layers)
    hipMemsetAsync(deg_i, 0, (size_t)N * 4, stream);
    k_hist<<<nb_e, 256, 0, stream>>>(dst, deg_i, E);
    k_dinv<<<nb_n, 256, 0, stream>>>(deg_i, dinv, N);
    k_scan1<<<nb_scan, 256, 0, stream>>>(deg_i, rowptr, bsum, N);
    k_scan2<<<1, 128, 0, stream>>>(bsum, nb_scan);
    k_scan3<<<nb_n, 256, 0, stream>>>(rowptr, bsum, N);
    k_fill<<<nb_e, 256, 0, stream>>>(src, dst, dinv, rowptr, csr_src, csr_w, E);
    // after k_fill: rowptr[d] = row END (original rowptr[d+1])

    // ---- layer 1: x (N x 7) -> bufH, agg init in bufA
    k_gemm_init<7, false><<<nb_gemm, 256, 0, stream>>>(x, W1, b1, dinv, bufH, bufA, N);
    k_aggregate<<<nb_agg, 256, 0, stream>>>(rowptr, csr_src, csr_w, bufH, bufA, N);

    // ---- layer 2
    k_gemm_init<HID, true><<<nb_gemm, 256, 0, stream>>>(bufA, W2, b2, dinv, bufH, bufA, N);
    k_aggregate<<<nb_agg, 256, 0, stream>>>(rowptr, csr_src, csr_w, bufH, bufA, N);

    // ---- layer 3
    k_gemm_init<HID, true><<<nb_gemm, 256, 0, stream>>>(bufA, W3, b3, dinv, bufH, bufA, N);
    k_aggregate<<<nb_agg, 256, 0, stream>>>(rowptr, csr_src, csr_w, bufH, bufA, N);

    // ---- mean-pool + head
    hipMemsetAsync(pool, 0, (size_t)(NGRAPHS * HID + NGRAPHS) * 4, stream);
    k_pool<<<nb_pool, 256, 0, stream>>>(bufA, batch, pool, cnt, N);
    k_head<<<2, 256, 0, stream>>>(pool, cnt, Wl, bl, out);
}

// Round 4
// 531.613 us; speedup vs baseline: 3.0061x; 1.2774x over previous
//
#include <hip/hip_runtime.h>

#define HID 64
#define NGRAPHS 256
#define SCAN_ELEMS 1024   // elements per scan block (256 thr x 4)

// ---- CSR build: histogram -> scan -> fill -------------------------------

__global__ __launch_bounds__(256) void k_hist(const int* __restrict__ dst,
                                              int* __restrict__ deg, int e) {
    int i = blockIdx.x * 256 + threadIdx.x;
    if (i < e) atomicAdd(&deg[dst[i]], 1);
}

__global__ __launch_bounds__(256) void k_dinv(const int* __restrict__ deg,
                                              float* __restrict__ dinv, int n) {
    int i = blockIdx.x * 256 + threadIdx.x;
    if (i < n) dinv[i] = rsqrtf((float)(deg[i] + 1));   // +1 self-loop
}

// exclusive scan, stage 1: per-block (1024 elems) scan + block totals
__global__ __launch_bounds__(256) void k_scan1(const int* __restrict__ deg,
                                               int* __restrict__ rowptr,
                                               int* __restrict__ bsum, int n) {
    __shared__ int sh[256];
    const int t = threadIdx.x;
    const int base = blockIdx.x * SCAN_ELEMS + t * 4;
    int v[4];
    int s = 0;
#pragma unroll
    for (int k = 0; k < 4; k++) {
        int i = base + k;
        v[k] = (i < n) ? deg[i] : 0;
        s += v[k];
    }
    sh[t] = s;
    __syncthreads();
#pragma unroll
    for (int off = 1; off < 256; off <<= 1) {
        int add = (t >= off) ? sh[t - off] : 0;
        __syncthreads();
        sh[t] += add;
        __syncthreads();
    }
    int run = sh[t] - s;    // exclusive prefix of this thread's chunk
#pragma unroll
    for (int k = 0; k < 4; k++) {
        int i = base + k;
        if (i < n) rowptr[i] = run;
        run += v[k];
    }
    if (t == 255) bsum[blockIdx.x] = sh[255];
}

// stage 2: exclusive scan of the (<=128) block totals, single block
__global__ __launch_bounds__(128) void k_scan2(int* __restrict__ bsum, int nb) {
    __shared__ int sh[128];
    const int t = threadIdx.x;
    int own = (t < nb) ? bsum[t] : 0;
    sh[t] = own;
    __syncthreads();
#pragma unroll
    for (int off = 1; off < 128; off <<= 1) {
        int add = (t >= off) ? sh[t - off] : 0;
        __syncthreads();
        sh[t] += add;
        __syncthreads();
    }
    if (t < nb) bsum[t] = sh[t] - own;
}

// stage 3: add block offsets
__global__ __launch_bounds__(256) void k_scan3(int* __restrict__ rowptr,
                                               const int* __restrict__ bsum, int n) {
    int i = blockIdx.x * 256 + threadIdx.x;
    if (i < n) rowptr[i] += bsum[i / SCAN_ELEMS];
}

// fill: pos = rowptr[d]++ ; after this pass rowptr[d] == row END of node d
__global__ __launch_bounds__(256) void k_fill(const int* __restrict__ src,
                                              const int* __restrict__ dst,
                                              const float* __restrict__ dinv,
                                              int* __restrict__ rowptr,
                                              int* __restrict__ csr_src,
                                              float* __restrict__ csr_w, int e) {
    int i = blockIdx.x * 256 + threadIdx.x;
    if (i >= e) return;
    int s = src[i], d = dst[i];
    int pos = atomicAdd(&rowptr[d], 1);
    csr_src[pos] = s;
    csr_w[pos] = dinv[s] * dinv[d];
}

// ---- per-layer dense transform: h = (relu?)act @ W ----------------------
// 16 nodes/block, each thread owns (channel, 4-node group) -> acc[4].
// LDS: W 16KB + act 4KB. Wsh reads 2-way (free), Ash reads wave-broadcast.

template <int K, bool RELU>
__global__ __launch_bounds__(256) void k_gemm(
        const float* __restrict__ act, const float* __restrict__ W,
        float* __restrict__ h, int n_nodes) {
    __shared__ float Wsh[K * HID];
    __shared__ float Ash[16 * K];
    const int t = threadIdx.x;
    const int n0 = blockIdx.x * 16;

    for (int i = t; i < K * HID; i += 256) Wsh[i] = W[i];
    const long long lim = (long long)(n_nodes - n0) * K;
    for (int i = t; i < 16 * K; i += 256) {
        float v = (i < lim) ? act[(size_t)n0 * K + i] : 0.0f;
        if (RELU) v = fmaxf(v, 0.0f);
        Ash[i] = v;
    }
    __syncthreads();

    const int c = t & 63;       // output channel
    const int g = t >> 6;       // node sub-group 0..3, 4 nodes each
    float acc[4] = {0.0f, 0.0f, 0.0f, 0.0f};
#pragma unroll 8
    for (int k = 0; k < K; k++) {
        float w = Wsh[k * HID + c];
#pragma unroll
        for (int i = 0; i < 4; i++) acc[i] += Ash[(g * 4 + i) * K + k] * w;
    }
#pragma unroll
    for (int i = 0; i < 4; i++) {
        int n = n0 + g * 4 + i;
        if (n < n_nodes) h[(size_t)n * HID + c] = acc[i];
    }
}

// ---- CSR aggregate: one wave per dst node, no atomics -------------------
// acc starts at b + h*dinv^2 (bias + self-loop folded here).

__global__ __launch_bounds__(256) void k_aggregate(
        const int* __restrict__ rowptr,      // post-fill: rowptr[d] = row END
        const int* __restrict__ csr_src, const float* __restrict__ csr_w,
        const float* __restrict__ h, const float* __restrict__ b,
        const float* __restrict__ dinv, float* __restrict__ agg, int n_nodes) {
    int wave = (blockIdx.x * 256 + threadIdx.x) >> 6;
    int lane = threadIdx.x & 63;
    if (wave >= n_nodes) return;
    int beg = (wave == 0) ? 0 : rowptr[wave - 1];
    int end = rowptr[wave];
    float dv = dinv[wave];
    float acc = b[lane] + h[(size_t)wave * HID + lane] * dv * dv;
    int j = beg;
    for (; j + 1 < end; j += 2) {                 // 2-wide for MLP
        int s0 = csr_src[j], s1 = csr_src[j + 1];
        float w0 = csr_w[j], w1 = csr_w[j + 1];
        float v0 = h[(size_t)s0 * HID + lane];
        float v1 = h[(size_t)s1 * HID + lane];
        acc += v0 * w0 + v1 * w1;
    }
    if (j < end) {
        int s = csr_src[j];
        acc += h[(size_t)s * HID + lane] * csr_w[j];
    }
    agg[(size_t)wave * HID + lane] = acc;
}

// ---- graph mean-pool: batch sorted -> register runs, few atomics --------

__global__ __launch_bounds__(256) void k_pool(
        const float* __restrict__ agg, const int* __restrict__ batch,
        float* __restrict__ pool, float* __restrict__ cnt, int n_nodes) {
    const int NPW = 64;                       // nodes per wave
    int wave = (blockIdx.x * 256 + threadIdx.x) >> 6;
    int lane = threadIdx.x & 63;
    int n0 = wave * NPW;
    if (n0 >= n_nodes) return;
    int nend = min(n0 + NPW, n_nodes);

    int g = batch[n0];
    float acc = 0.0f;
    int cn = 0;
    for (int n = n0; n < nend; n++) {
        int gn = batch[n];
        if (gn != g) {                         // run boundary: flush
            atomicAdd(&pool[g * HID + lane], acc);
            if (lane == 0) atomicAdd(&cnt[g], (float)cn);
            acc = 0.0f; cn = 0; g = gn;
        }
        acc += agg[(size_t)n * HID + lane];
        cn++;
    }
    atomicAdd(&pool[g * HID + lane], acc);
    if (lane == 0) atomicAdd(&cnt[g], (float)cn);
}

// ---- final head ---------------------------------------------------------

__global__ __launch_bounds__(256) void k_head(
        const float* __restrict__ pool, const float* __restrict__ cnt,
        const float* __restrict__ Wl, const float* __restrict__ bl,
        float* __restrict__ out) {
    int t = blockIdx.x * 256 + threadIdx.x;   // 0..511
    if (t >= NGRAPHS * 2) return;
    int g = t >> 1, o = t & 1;
    float c = fmaxf(cnt[g], 1.0f);
    float acc = 0.0f;
#pragma unroll
    for (int k = 0; k < HID; k++) acc += pool[g * HID + k] * Wl[k * 2 + o];
    out[t] = acc / c + bl[o];
}

// -------------------------------------------------------------------------

extern "C" void kernel_launch(void* const* d_in, const int* in_sizes, int n_in,
                              void* d_out, int out_size, void* d_ws, size_t ws_size,
                              hipStream_t stream) {
    const float* x     = (const float*)d_in[0];
    const int*   ei    = (const int*)d_in[1];
    const int*   batch = (const int*)d_in[2];
    const float* W1    = (const float*)d_in[3];
    const float* b1    = (const float*)d_in[4];
    const float* W2    = (const float*)d_in[5];
    const float* b2    = (const float*)d_in[6];
    const float* W3    = (const float*)d_in[7];
    const float* b3    = (const float*)d_in[8];
    const float* Wl    = (const float*)d_in[9];
    const float* bl    = (const float*)d_in[10];
    float* out = (float*)d_out;

    const int N = in_sizes[0] / 7;     // 100000
    const int E = in_sizes[1] / 2;     // 1250000
    const int* src = ei;
    const int* dst = ei + E;

    // workspace carve-out (256B aligned)
    char* ws = (char*)d_ws;
    size_t off = 0;
    auto carve = [&](size_t bytes) {
        void* p = ws + off;
        off = (off + bytes + 255) & ~(size_t)255;
        return p;
    };
    int*   deg_i   = (int*)carve((size_t)N * 4);
    float* dinv    = (float*)carve((size_t)N * 4);
    int*   rowptr  = (int*)carve((size_t)N * 4);
    int*   bsum    = (int*)carve(512 * 4);
    int*   csr_src = (int*)carve((size_t)E * 4);
    float* csr_w   = (float*)carve((size_t)E * 4);
    float* bufH    = (float*)carve((size_t)N * HID * 4);
    float* bufA    = (float*)carve((size_t)N * HID * 4);
    float* pool    = (float*)carve((size_t)(NGRAPHS * HID + NGRAPHS) * 4);
    float* cnt     = pool + NGRAPHS * HID;

    const int nb_n = (N + 255) / 256;
    const int nb_e = (E + 255) / 256;
    const int nb_gemm = (N + 15) / 16;                       // 6250
    const int nb_scan = (N + SCAN_ELEMS - 1) / SCAN_ELEMS;   // 98
    const int nb_agg  = (N + 3) / 4;       // 4 waves (nodes) per block
    const int nb_pool = (N + 64 * 4 - 1) / (64 * 4);

    // ---- CSR build (once, reused by all 3 layers)
    hipMemsetAsync(deg_i, 0, (size_t)N * 4, stream);
    k_hist<<<nb_e, 256, 0, stream>>>(dst, deg_i, E);
    k_dinv<<<nb_n, 256, 0, stream>>>(deg_i, dinv, N);
    k_scan1<<<nb_scan, 256, 0, stream>>>(deg_i, rowptr, bsum, N);
    k_scan2<<<1, 128, 0, stream>>>(bsum, nb_scan);
    k_scan3<<<nb_n, 256, 0, stream>>>(rowptr, bsum, N);
    k_fill<<<nb_e, 256, 0, stream>>>(src, dst, dinv, rowptr, csr_src, csr_w, E);
    // after k_fill: rowptr[d] = row END (original rowptr[d+1])

    // ---- layer 1: x (N x 7) -> bufH; aggregate -> bufA
    k_gemm<7, false><<<nb_gemm, 256, 0, stream>>>(x, W1, bufH, N);
    k_aggregate<<<nb_agg, 256, 0, stream>>>(rowptr, csr_src, csr_w, bufH, b1, dinv, bufA, N);

    // ---- layer 2: relu(bufA) @ W2 -> bufH; aggregate -> bufA
    k_gemm<HID, true><<<nb_gemm, 256, 0, stream>>>(bufA, W2, bufH, N);
    k_aggregate<<<nb_agg, 256, 0, stream>>>(rowptr, csr_src, csr_w, bufH, b2, dinv, bufA, N);

    // ---- layer 3
    k_gemm<HID, true><<<nb_gemm, 256, 0, stream>>>(bufA, W3, bufH, N);
    k_aggregate<<<nb_agg, 256, 0, stream>>>(rowptr, csr_src, csr_w, bufH, b3, dinv, bufA, N);

    // ---- mean-pool + head
    hipMemsetAsync(pool, 0, (size_t)(NGRAPHS * HID + NGRAPHS) * 4, stream);
    k_pool<<<nb_pool, 256, 0, stream>>>(bufA, batch, pool, cnt, N);
    k_head<<<2, 256, 0, stream>>>(pool, cnt, Wl, bl, out);
}

// Round 5
// 489.133 us; speedup vs baseline: 3.2672x; 1.0868x over previous
//
#include <hip/hip_runtime.h>

#define HID 64
#define NGRAPHS 256
#define SCAN_ELEMS 1024   // elements per scan block (256 thr x 4)

// ---- CSR build: histogram -> scan -> fill -------------------------------

__global__ __launch_bounds__(256) void k_hist(const int* __restrict__ dst,
                                              int* __restrict__ deg, int e) {
    int i = blockIdx.x * 256 + threadIdx.x;
    if (i < e) atomicAdd(&deg[dst[i]], 1);
}

__global__ __launch_bounds__(256) void k_dinv(const int* __restrict__ deg,
                                              float* __restrict__ dinv, int n) {
    int i = blockIdx.x * 256 + threadIdx.x;
    if (i < n) dinv[i] = rsqrtf((float)(deg[i] + 1));   // +1 self-loop
}

// exclusive scan, stage 1: per-block (1024 elems) scan + block totals
__global__ __launch_bounds__(256) void k_scan1(const int* __restrict__ deg,
                                               int* __restrict__ rowptr,
                                               int* __restrict__ bsum, int n) {
    __shared__ int sh[256];
    const int t = threadIdx.x;
    const int base = blockIdx.x * SCAN_ELEMS + t * 4;
    int v[4];
    int s = 0;
#pragma unroll
    for (int k = 0; k < 4; k++) {
        int i = base + k;
        v[k] = (i < n) ? deg[i] : 0;
        s += v[k];
    }
    sh[t] = s;
    __syncthreads();
#pragma unroll
    for (int off = 1; off < 256; off <<= 1) {
        int add = (t >= off) ? sh[t - off] : 0;
        __syncthreads();
        sh[t] += add;
        __syncthreads();
    }
    int run = sh[t] - s;    // exclusive prefix of this thread's chunk
#pragma unroll
    for (int k = 0; k < 4; k++) {
        int i = base + k;
        if (i < n) rowptr[i] = run;
        run += v[k];
    }
    if (t == 255) bsum[blockIdx.x] = sh[255];
}

// stage 2: exclusive scan of the (<=128) block totals, single block
__global__ __launch_bounds__(128) void k_scan2(int* __restrict__ bsum, int nb) {
    __shared__ int sh[128];
    const int t = threadIdx.x;
    int own = (t < nb) ? bsum[t] : 0;
    sh[t] = own;
    __syncthreads();
#pragma unroll
    for (int off = 1; off < 128; off <<= 1) {
        int add = (t >= off) ? sh[t - off] : 0;
        __syncthreads();
        sh[t] += add;
        __syncthreads();
    }
    if (t < nb) bsum[t] = sh[t] - own;
}

// stage 3: add block offsets
__global__ __launch_bounds__(256) void k_scan3(int* __restrict__ rowptr,
                                               const int* __restrict__ bsum, int n) {
    int i = blockIdx.x * 256 + threadIdx.x;
    if (i < n) rowptr[i] += bsum[i / SCAN_ELEMS];
}

// fill: pos = rowptr[d]++ ; ONE 8B packed write per edge {src, w_bits}.
// after this pass rowptr[d] == row END of node d
__global__ __launch_bounds__(256) void k_fill(const int* __restrict__ src,
                                              const int* __restrict__ dst,
                                              const float* __restrict__ dinv,
                                              int* __restrict__ rowptr,
                                              int2* __restrict__ csr, int e) {
    int i = blockIdx.x * 256 + threadIdx.x;
    if (i >= e) return;
    int s = src[i], d = dst[i];
    int pos = atomicAdd(&rowptr[d], 1);
    float w = dinv[s] * dinv[d];
    csr[pos] = make_int2(s, __float_as_int(w));
}

// ---- per-layer dense transform: h = (relu?)act @ W ----------------------

template <int K, bool RELU>
__global__ __launch_bounds__(256) void k_gemm(
        const float* __restrict__ act, const float* __restrict__ W,
        float* __restrict__ h, int n_nodes) {
    __shared__ float Wsh[K * HID];
    __shared__ float Ash[16 * K];
    const int t = threadIdx.x;
    const int n0 = blockIdx.x * 16;

    for (int i = t; i < K * HID; i += 256) Wsh[i] = W[i];
    const long long lim = (long long)(n_nodes - n0) * K;
    for (int i = t; i < 16 * K; i += 256) {
        float v = (i < lim) ? act[(size_t)n0 * K + i] : 0.0f;
        if (RELU) v = fmaxf(v, 0.0f);
        Ash[i] = v;
    }
    __syncthreads();

    const int c = t & 63;       // output channel
    const int g = t >> 6;       // node sub-group 0..3, 4 nodes each
    float acc[4] = {0.0f, 0.0f, 0.0f, 0.0f};
#pragma unroll 8
    for (int k = 0; k < K; k++) {
        float w = Wsh[k * HID + c];
#pragma unroll
        for (int i = 0; i < 4; i++) acc[i] += Ash[(g * 4 + i) * K + k] * w;
    }
#pragma unroll
    for (int i = 0; i < 4; i++) {
        int n = n0 + g * 4 + i;
        if (n < n_nodes) h[(size_t)n * HID + c] = acc[i];
    }
}

// ---- CSR aggregate: one wave per dst node, no atomics, 4-wide MLP -------
// acc starts at b + h*dinv^2 (bias + self-loop folded here).

__global__ __launch_bounds__(256) void k_aggregate(
        const int* __restrict__ rowptr,      // post-fill: rowptr[d] = row END
        const int2* __restrict__ csr,
        const float* __restrict__ h, const float* __restrict__ b,
        const float* __restrict__ dinv, float* __restrict__ agg, int n_nodes) {
    int wave = (blockIdx.x * 256 + threadIdx.x) >> 6;
    int lane = threadIdx.x & 63;
    if (wave >= n_nodes) return;
    int beg = (wave == 0) ? 0 : rowptr[wave - 1];
    int end = rowptr[wave];
    float dv = dinv[wave];
    float acc = b[lane] + h[(size_t)wave * HID + lane] * dv * dv;
    int j = beg;
    for (; j + 3 < end; j += 4) {                 // 4 outstanding gathers
        int2 e0 = csr[j], e1 = csr[j + 1], e2 = csr[j + 2], e3 = csr[j + 3];
        float v0 = h[(size_t)e0.x * HID + lane];
        float v1 = h[(size_t)e1.x * HID + lane];
        float v2 = h[(size_t)e2.x * HID + lane];
        float v3 = h[(size_t)e3.x * HID + lane];
        acc += v0 * __int_as_float(e0.y) + v1 * __int_as_float(e1.y)
             + v2 * __int_as_float(e2.y) + v3 * __int_as_float(e3.y);
    }
    for (; j < end; j++) {
        int2 e0 = csr[j];
        acc += h[(size_t)e0.x * HID + lane] * __int_as_float(e0.y);
    }
    agg[(size_t)wave * HID + lane] = acc;
}

// ---- graph mean-pool: batch sorted -> register runs, few atomics --------

__global__ __launch_bounds__(256) void k_pool(
        const float* __restrict__ agg, const int* __restrict__ batch,
        float* __restrict__ pool, float* __restrict__ cnt, int n_nodes) {
    const int NPW = 64;                       // nodes per wave
    int wave = (blockIdx.x * 256 + threadIdx.x) >> 6;
    int lane = threadIdx.x & 63;
    int n0 = wave * NPW;
    if (n0 >= n_nodes) return;
    int nend = min(n0 + NPW, n_nodes);

    int g = batch[n0];
    float acc = 0.0f;
    int cn = 0;
    for (int n = n0; n < nend; n++) {
        int gn = batch[n];
        if (gn != g) {                         // run boundary: flush
            atomicAdd(&pool[g * HID + lane], acc);
            if (lane == 0) atomicAdd(&cnt[g], (float)cn);
            acc = 0.0f; cn = 0; g = gn;
        }
        acc += agg[(size_t)n * HID + lane];
        cn++;
    }
    atomicAdd(&pool[g * HID + lane], acc);
    if (lane == 0) atomicAdd(&cnt[g], (float)cn);
}

// ---- final head ---------------------------------------------------------

__global__ __launch_bounds__(256) void k_head(
        const float* __restrict__ pool, const float* __restrict__ cnt,
        const float* __restrict__ Wl, const float* __restrict__ bl,
        float* __restrict__ out) {
    int t = blockIdx.x * 256 + threadIdx.x;   // 0..511
    if (t >= NGRAPHS * 2) return;
    int g = t >> 1, o = t & 1;
    float c = fmaxf(cnt[g], 1.0f);
    float acc = 0.0f;
#pragma unroll
    for (int k = 0; k < HID; k++) acc += pool[g * HID + k] * Wl[k * 2 + o];
    out[t] = acc / c + bl[o];
}

// -------------------------------------------------------------------------

extern "C" void kernel_launch(void* const* d_in, const int* in_sizes, int n_in,
                              void* d_out, int out_size, void* d_ws, size_t ws_size,
                              hipStream_t stream) {
    const float* x     = (const float*)d_in[0];
    const int*   ei    = (const int*)d_in[1];
    const int*   batch = (const int*)d_in[2];
    const float* W1    = (const float*)d_in[3];
    const float* b1    = (const float*)d_in[4];
    const float* W2    = (const float*)d_in[5];
    const float* b2    = (const float*)d_in[6];
    const float* W3    = (const float*)d_in[7];
    const float* b3    = (const float*)d_in[8];
    const float* Wl    = (const float*)d_in[9];
    const float* bl    = (const float*)d_in[10];
    float* out = (float*)d_out;

    const int N = in_sizes[0] / 7;     // 100000
    const int E = in_sizes[1] / 2;     // 1250000
    const int* src = ei;
    const int* dst = ei + E;

    // workspace carve-out (256B aligned)
    char* ws = (char*)d_ws;
    size_t off = 0;
    auto carve = [&](size_t bytes) {
        void* p = ws + off;
        off = (off + bytes + 255) & ~(size_t)255;
        return p;
    };
    int*   deg_i   = (int*)carve((size_t)N * 4);
    float* dinv    = (float*)carve((size_t)N * 4);
    int*   rowptr  = (int*)carve((size_t)N * 4);
    int*   bsum    = (int*)carve(512 * 4);
    int2*  csr     = (int2*)carve((size_t)E * 8);
    float* bufH    = (float*)carve((size_t)N * HID * 4);
    float* bufA    = (float*)carve((size_t)N * HID * 4);
    float* pool    = (float*)carve((size_t)(NGRAPHS * HID + NGRAPHS) * 4);
    float* cnt     = pool + NGRAPHS * HID;

    const int nb_n = (N + 255) / 256;
    const int nb_e = (E + 255) / 256;
    const int nb_gemm = (N + 15) / 16;                       // 6250
    const int nb_scan = (N + SCAN_ELEMS - 1) / SCAN_ELEMS;   // 98
    const int nb_agg  = (N + 3) / 4;       // 4 waves (nodes) per block
    const int nb_pool = (N + 64 * 4 - 1) / (64 * 4);

    // ---- CSR build (once, reused by all 3 layers)
    hipMemsetAsync(deg_i, 0, (size_t)N * 4, stream);
    k_hist<<<nb_e, 256, 0, stream>>>(dst, deg_i, E);
    k_dinv<<<nb_n, 256, 0, stream>>>(deg_i, dinv, N);
    k_scan1<<<nb_scan, 256, 0, stream>>>(deg_i, rowptr, bsum, N);
    k_scan2<<<1, 128, 0, stream>>>(bsum, nb_scan);
    k_scan3<<<nb_n, 256, 0, stream>>>(rowptr, bsum, N);
    k_fill<<<nb_e, 256, 0, stream>>>(src, dst, dinv, rowptr, csr, E);
    // after k_fill: rowptr[d] = row END (original rowptr[d+1])

    // ---- layer 1: x (N x 7) -> bufH; aggregate -> bufA
    k_gemm<7, false><<<nb_gemm, 256, 0, stream>>>(x, W1, bufH, N);
    k_aggregate<<<nb_agg, 256, 0, stream>>>(rowptr, csr, bufH, b1, dinv, bufA, N);

    // ---- layer 2: relu(bufA) @ W2 -> bufH; aggregate -> bufA
    k_gemm<HID, true><<<nb_gemm, 256, 0, stream>>>(bufA, W2, bufH, N);
    k_aggregate<<<nb_agg, 256, 0, stream>>>(rowptr, csr, bufH, b2, dinv, bufA, N);

    // ---- layer 3
    k_gemm<HID, true><<<nb_gemm, 256, 0, stream>>>(bufA, W3, bufH, N);
    k_aggregate<<<nb_agg, 256, 0, stream>>>(rowptr, csr, bufH, b3, dinv, bufA, N);

    // ---- mean-pool + head
    hipMemsetAsync(pool, 0, (size_t)(NGRAPHS * HID + NGRAPHS) * 4, stream);
    k_pool<<<nb_pool, 256, 0, stream>>>(bufA, batch, pool, cnt, N);
    k_head<<<2, 256, 0, stream>>>(pool, cnt, Wl, bl, out);
}

// Round 6
// 405.278 us; speedup vs baseline: 3.9431x; 1.2069x over previous
//
#include <hip/hip_runtime.h>

#define HID 64
#define NGRAPHS 256
#define SCAN_ELEMS 1024   // elements per scan block (256 thr x 4)

// ---- hist + rank: rank[i] = within-row arrival order of edge i ----------

__global__ __launch_bounds__(256) void k_hist(const int* __restrict__ dst,
                                              int* __restrict__ deg,
                                              int* __restrict__ rank, int e) {
    int i = blockIdx.x * 256 + threadIdx.x;
    if (i < e) rank[i] = atomicAdd(&deg[dst[i]], 1);
}

// ---- scan stage 1 (+ dinv fused): per-block exclusive scan over n1=N+1 --

__global__ __launch_bounds__(256) void k_scan1(const int* __restrict__ deg,
                                               int* __restrict__ rowptr,
                                               int* __restrict__ bsum,
                                               float* __restrict__ dinv,
                                               int n1) {
    __shared__ int sh[256];
    const int t = threadIdx.x;
    const int base = blockIdx.x * SCAN_ELEMS + t * 4;
    int v[4];
    int s = 0;
#pragma unroll
    for (int k = 0; k < 4; k++) {
        int i = base + k;
        v[k] = (i < n1) ? deg[i] : 0;
        if (i < n1 - 1) dinv[i] = rsqrtf((float)(v[k] + 1));  // +1 self-loop
        s += v[k];
    }
    sh[t] = s;
    __syncthreads();
#pragma unroll
    for (int off = 1; off < 256; off <<= 1) {
        int add = (t >= off) ? sh[t - off] : 0;
        __syncthreads();
        sh[t] += add;
        __syncthreads();
    }
    int run = sh[t] - s;    // exclusive prefix of this thread's chunk
#pragma unroll
    for (int k = 0; k < 4; k++) {
        int i = base + k;
        if (i < n1) rowptr[i] = run;
        run += v[k];
    }
    if (t == 255) bsum[blockIdx.x] = sh[255];
}

// ---- scan stage 2: exclusive scan of (<=128) block totals ---------------

__global__ __launch_bounds__(128) void k_scan2(int* __restrict__ bsum, int nb) {
    __shared__ int sh[128];
    const int t = threadIdx.x;
    int own = (t < nb) ? bsum[t] : 0;
    sh[t] = own;
    __syncthreads();
#pragma unroll
    for (int off = 1; off < 128; off <<= 1) {
        int add = (t >= off) ? sh[t - off] : 0;
        __syncthreads();
        sh[t] += add;
        __syncthreads();
    }
    if (t < nb) bsum[t] = sh[t] - own;
}

// ---- fill: NO atomic. pos = rowptr[d] + bsum[d>>10] + rank. 4 edges/thr -

__global__ __launch_bounds__(256) void k_fill(const int* __restrict__ src,
                                              const int* __restrict__ dst,
                                              const int* __restrict__ rank,
                                              const int* __restrict__ rowptr,
                                              const int* __restrict__ bsum,
                                              const float* __restrict__ dinv,
                                              int2* __restrict__ csr, int e) {
    int base = (blockIdx.x * 256 + threadIdx.x) * 4;
    if (base + 3 < e) {
        int4 s4 = *(const int4*)(src + base);
        int4 d4 = *(const int4*)(dst + base);
        int4 r4 = *(const int4*)(rank + base);
        int s[4] = {s4.x, s4.y, s4.z, s4.w};
        int d[4] = {d4.x, d4.y, d4.z, d4.w};
        int r[4] = {r4.x, r4.y, r4.z, r4.w};
#pragma unroll
        for (int k = 0; k < 4; k++) {
            int pos = rowptr[d[k]] + bsum[d[k] >> 10] + r[k];
            float w = dinv[s[k]] * dinv[d[k]];
            csr[pos] = make_int2(s[k], __float_as_int(w));
        }
    } else {
        for (int i = base; i < e; i++) {
            int s = src[i], d = dst[i];
            int pos = rowptr[d] + bsum[d >> 10] + rank[i];
            csr[pos] = make_int2(s, __float_as_int(dinv[s] * dinv[d]));
        }
    }
}

// ---- per-layer dense transform: h = (relu?)act @ W ----------------------

template <int K, bool RELU>
__global__ __launch_bounds__(256) void k_gemm(
        const float* __restrict__ act, const float* __restrict__ W,
        float* __restrict__ h, int n_nodes) {
    __shared__ float Wsh[K * HID];
    __shared__ float Ash[16 * K];
    const int t = threadIdx.x;
    const int n0 = blockIdx.x * 16;

    for (int i = t; i < K * HID; i += 256) Wsh[i] = W[i];
    const long long lim = (long long)(n_nodes - n0) * K;
    for (int i = t; i < 16 * K; i += 256) {
        float v = (i < lim) ? act[(size_t)n0 * K + i] : 0.0f;
        if (RELU) v = fmaxf(v, 0.0f);
        Ash[i] = v;
    }
    __syncthreads();

    const int c = t & 63;       // output channel
    const int g = t >> 6;       // node sub-group 0..3, 4 nodes each
    float acc[4] = {0.0f, 0.0f, 0.0f, 0.0f};
#pragma unroll 8
    for (int k = 0; k < K; k++) {
        float w = Wsh[k * HID + c];
#pragma unroll
        for (int i = 0; i < 4; i++) acc[i] += Ash[(g * 4 + i) * K + k] * w;
    }
#pragma unroll
    for (int i = 0; i < 4; i++) {
        int n = n0 + g * 4 + i;
        if (n < n_nodes) h[(size_t)n * HID + c] = acc[i];
    }
}

// ---- CSR aggregate: float4 lanes, 16 lanes/node, 4 nodes/wave, 4-wide ---
// One gather instruction fetches 4 full 256B rows; 4 in flight per wave.
// acc starts at b + h*dinv^2 (bias + self-loop folded here).

__global__ __launch_bounds__(256) void k_aggregate(
        const int* __restrict__ rowptr,      // exclusive, N+1 entries (partial)
        const int* __restrict__ bsum,
        const int2* __restrict__ csr,
        const float* __restrict__ h, const float* __restrict__ b,
        const float* __restrict__ dinv, float* __restrict__ agg, int n_nodes) {
    int gtid = blockIdx.x * 256 + threadIdx.x;
    int node = (gtid >> 6) * 4 + ((threadIdx.x >> 4) & 3);
    int l16 = threadIdx.x & 15;
    if (node >= n_nodes) return;
    int beg = rowptr[node] + bsum[node >> 10];
    int end = rowptr[node + 1] + bsum[(node + 1) >> 10];
    const float4* h4 = (const float4*)h;
    const float4* b4 = (const float4*)b;
    float dv = dinv[node];
    float sc = dv * dv;
    float4 hb = h4[(size_t)node * 16 + l16];
    float4 bb = b4[l16];
    float4 acc = make_float4(bb.x + hb.x * sc, bb.y + hb.y * sc,
                             bb.z + hb.z * sc, bb.w + hb.w * sc);
    int j = beg;
    for (; j + 3 < end; j += 4) {
        int2 e0 = csr[j], e1 = csr[j + 1], e2 = csr[j + 2], e3 = csr[j + 3];
        float4 v0 = h4[(size_t)e0.x * 16 + l16];
        float4 v1 = h4[(size_t)e1.x * 16 + l16];
        float4 v2 = h4[(size_t)e2.x * 16 + l16];
        float4 v3 = h4[(size_t)e3.x * 16 + l16];
        float w0 = __int_as_float(e0.y), w1 = __int_as_float(e1.y);
        float w2 = __int_as_float(e2.y), w3 = __int_as_float(e3.y);
        acc.x += v0.x * w0 + v1.x * w1 + v2.x * w2 + v3.x * w3;
        acc.y += v0.y * w0 + v1.y * w1 + v2.y * w2 + v3.y * w3;
        acc.z += v0.z * w0 + v1.z * w1 + v2.z * w2 + v3.z * w3;
        acc.w += v0.w * w0 + v1.w * w1 + v2.w * w2 + v3.w * w3;
    }
    for (; j < end; j++) {
        int2 e0 = csr[j];
        float4 v = h4[(size_t)e0.x * 16 + l16];
        float w = __int_as_float(e0.y);
        acc.x += v.x * w; acc.y += v.y * w; acc.z += v.z * w; acc.w += v.w * w;
    }
    ((float4*)agg)[(size_t)node * 16 + l16] = acc;
}

// ---- graph mean-pool: batch sorted -> register runs, few atomics --------

__global__ __launch_bounds__(256) void k_pool(
        const float* __restrict__ agg, const int* __restrict__ batch,
        float* __restrict__ pool, float* __restrict__ cnt, int n_nodes) {
    const int NPW = 64;                       // nodes per wave
    int wave = (blockIdx.x * 256 + threadIdx.x) >> 6;
    int lane = threadIdx.x & 63;
    int n0 = wave * NPW;
    if (n0 >= n_nodes) return;
    int nend = min(n0 + NPW, n_nodes);

    int g = batch[n0];
    float acc = 0.0f;
    int cn = 0;
    for (int n = n0; n < nend; n++) {
        int gn = batch[n];
        if (gn != g) {                         // run boundary: flush
            atomicAdd(&pool[g * HID + lane], acc);
            if (lane == 0) atomicAdd(&cnt[g], (float)cn);
            acc = 0.0f; cn = 0; g = gn;
        }
        acc += agg[(size_t)n * HID + lane];
        cn++;
    }
    atomicAdd(&pool[g * HID + lane], acc);
    if (lane == 0) atomicAdd(&cnt[g], (float)cn);
}

// ---- final head ---------------------------------------------------------

__global__ __launch_bounds__(256) void k_head(
        const float* __restrict__ pool, const float* __restrict__ cnt,
        const float* __restrict__ Wl, const float* __restrict__ bl,
        float* __restrict__ out) {
    int t = blockIdx.x * 256 + threadIdx.x;   // 0..511
    if (t >= NGRAPHS * 2) return;
    int g = t >> 1, o = t & 1;
    float c = fmaxf(cnt[g], 1.0f);
    float acc = 0.0f;
#pragma unroll
    for (int k = 0; k < HID; k++) acc += pool[g * HID + k] * Wl[k * 2 + o];
    out[t] = acc / c + bl[o];
}

// -------------------------------------------------------------------------

extern "C" void kernel_launch(void* const* d_in, const int* in_sizes, int n_in,
                              void* d_out, int out_size, void* d_ws, size_t ws_size,
                              hipStream_t stream) {
    const float* x     = (const float*)d_in[0];
    const int*   ei    = (const int*)d_in[1];
    const int*   batch = (const int*)d_in[2];
    const float* W1    = (const float*)d_in[3];
    const float* b1    = (const float*)d_in[4];
    const float* W2    = (const float*)d_in[5];
    const float* b2    = (const float*)d_in[6];
    const float* W3    = (const float*)d_in[7];
    const float* b3    = (const float*)d_in[8];
    const float* Wl    = (const float*)d_in[9];
    const float* bl    = (const float*)d_in[10];
    float* out = (float*)d_out;

    const int N = in_sizes[0] / 7;     // 100000
    const int E = in_sizes[1] / 2;     // 1250000
    const int* src = ei;
    const int* dst = ei + E;

    // workspace carve-out (256B aligned)
    char* ws = (char*)d_ws;
    size_t off = 0;
    auto carve = [&](size_t bytes) {
        void* p = ws + off;
        off = (off + bytes + 255) & ~(size_t)255;
        return p;
    };
    int*   deg_i   = (int*)carve((size_t)(N + 1) * 4);
    float* dinv    = (float*)carve((size_t)N * 4);
    int*   rowptr  = (int*)carve((size_t)(N + 1) * 4);
    int*   bsum    = (int*)carve(512 * 4);
    int*   rank    = (int*)carve((size_t)E * 4);
    int2*  csr     = (int2*)carve((size_t)E * 8);
    float* bufH    = (float*)carve((size_t)N * HID * 4);
    float* bufA    = (float*)carve((size_t)N * HID * 4);
    float* pool    = (float*)carve((size_t)(NGRAPHS * HID + NGRAPHS) * 4);
    float* cnt     = pool + NGRAPHS * HID;

    const int nb_e = (E + 255) / 256;
    const int nb_gemm = (N + 15) / 16;                           // 6250
    const int nb_scan = (N + 1 + SCAN_ELEMS - 1) / SCAN_ELEMS;   // 98
    const int nb_fill = (E / 4 + 255) / 256;
    const int nb_agg  = (N + 15) / 16;     // 16 nodes per block (4/wave)
    const int nb_pool = (N + 64 * 4 - 1) / (64 * 4);

    // ---- CSR build (once, reused by all 3 layers)
    hipMemsetAsync(deg_i, 0, (size_t)(N + 1) * 4, stream);
    k_hist<<<nb_e, 256, 0, stream>>>(dst, deg_i, rank, E);
    k_scan1<<<nb_scan, 256, 0, stream>>>(deg_i, rowptr, bsum, dinv, N + 1);
    k_scan2<<<1, 128, 0, stream>>>(bsum, nb_scan);
    k_fill<<<nb_fill, 256, 0, stream>>>(src, dst, rank, rowptr, bsum, dinv, csr, E);

    // ---- layer 1: x (N x 7) -> bufH; aggregate -> bufA
    k_gemm<7, false><<<nb_gemm, 256, 0, stream>>>(x, W1, bufH, N);
    k_aggregate<<<nb_agg, 256, 0, stream>>>(rowptr, bsum, csr, bufH, b1, dinv, bufA, N);

    // ---- layer 2: relu(bufA) @ W2 -> bufH; aggregate -> bufA
    k_gemm<HID, true><<<nb_gemm, 256, 0, stream>>>(bufA, W2, bufH, N);
    k_aggregate<<<nb_agg, 256, 0, stream>>>(rowptr, bsum, csr, bufH, b2, dinv, bufA, N);

    // ---- layer 3
    k_gemm<HID, true><<<nb_gemm, 256, 0, stream>>>(bufA, W3, bufH, N);
    k_aggregate<<<nb_agg, 256, 0, stream>>>(rowptr, bsum, csr, bufH, b3, dinv, bufA, N);

    // ---- mean-pool + head
    hipMemsetAsync(pool, 0, (size_t)(NGRAPHS * HID + NGRAPHS) * 4, stream);
    k_pool<<<nb_pool, 256, 0, stream>>>(bufA, batch, pool, cnt, N);
    k_head<<<2, 256, 0, stream>>>(pool, cnt, Wl, bl, out);
}